// Round 3
// baseline (79791.327 us; speedup 1.0000x reference)
//
#include <hip/hip_runtime.h>
#include <math.h>
#include <stdint.h>

// ---------------- workspace layout (float32 indices) ----------------
// [0, 12288)            xg   [2 dir][6 vocab][1024 rows]
// [12288, 20480)        gate mailbox: [2 dir][2 parity][256 elem][4 type] of 8B (value,stamp)
// [20480, 20992)        stateH [2][256]
// [20992, 21504)        stateC [2][256]
// [21504, 1070080)      hist  [2 dir][2048 t][256]
// [1070080, 1070144)    ce partials [16 blk][4 wg]
// [1070144, 1070208)    ent partials [16 blk][4 wg]
static constexpr int XG_OFF   = 0;
static constexpr int GP_OFF_F = 12288;    // float index where mailbox starts (ull-aligned)
static constexpr int SH_OFF   = 20480;
static constexpr int SC_OFF   = 20992;
static constexpr int HIST_OFF = 21504;
static constexpr int HIST_D   = 524288;   // per-dir floats (2048*256)
static constexpr int CEP_OFF  = 1070080;
static constexpr int ENTP_OFF = 1070144;

// d_out layout (float32): [0,32768) sampled idx; 32768 ce; 32769 ent;
// [32770,33282) h (fwd then bwd); [33282,33794) c
static constexpr int OUT_CE = 32768;
static constexpr int OUT_H  = 32770;
static constexpr int OUT_C  = 33282;

// ---------------- exact JAX threefry2x32 (20 rounds) ----------------
__device__ __forceinline__ uint32_t rotl32(uint32_t v, int n) {
  return (v << n) | (v >> (32 - n));
}
__device__ __forceinline__ void tf2x32(uint32_t k0, uint32_t k1,
                                       uint32_t x0, uint32_t x1,
                                       uint32_t& y0, uint32_t& y1) {
  const uint32_t k2 = k0 ^ k1 ^ 0x1BD11BDAu;
  x0 += k0; x1 += k1;
  // rounds 1-4
  x0 += x1; x1 = rotl32(x1, 13); x1 ^= x0;
  x0 += x1; x1 = rotl32(x1, 15); x1 ^= x0;
  x0 += x1; x1 = rotl32(x1, 26); x1 ^= x0;
  x0 += x1; x1 = rotl32(x1, 6);  x1 ^= x0;
  x0 += k1; x1 += k2 + 1u;
  // rounds 5-8
  x0 += x1; x1 = rotl32(x1, 17); x1 ^= x0;
  x0 += x1; x1 = rotl32(x1, 29); x1 ^= x0;
  x0 += x1; x1 = rotl32(x1, 16); x1 ^= x0;
  x0 += x1; x1 = rotl32(x1, 24); x1 ^= x0;
  x0 += k2; x1 += k0 + 2u;
  // rounds 9-12
  x0 += x1; x1 = rotl32(x1, 13); x1 ^= x0;
  x0 += x1; x1 = rotl32(x1, 15); x1 ^= x0;
  x0 += x1; x1 = rotl32(x1, 26); x1 ^= x0;
  x0 += x1; x1 = rotl32(x1, 6);  x1 ^= x0;
  x0 += k0; x1 += k1 + 3u;
  // rounds 13-16
  x0 += x1; x1 = rotl32(x1, 17); x1 ^= x0;
  x0 += x1; x1 = rotl32(x1, 29); x1 ^= x0;
  x0 += x1; x1 = rotl32(x1, 16); x1 ^= x0;
  x0 += x1; x1 = rotl32(x1, 24); x1 ^= x0;
  x0 += k1; x1 += k2 + 4u;
  // rounds 17-20
  x0 += x1; x1 = rotl32(x1, 13); x1 ^= x0;
  x0 += x1; x1 = rotl32(x1, 15); x1 ^= x0;
  x0 += x1; x1 = rotl32(x1, 26); x1 ^= x0;
  x0 += x1; x1 = rotl32(x1, 6);  x1 ^= x0;
  x0 += k2; x1 += k0 + 5u;
  y0 = x0; y1 = x1;
}

// gumbel = -log(-log(uniform(bits))), matching JAX's f32 rounding steps
__device__ __forceinline__ float gumbel_from_bits(uint32_t bits) {
  float f = __uint_as_float(0x3f800000u | (bits >> 9)) - 1.0f;
  const float tiny = __uint_as_float(0x00800000u);  // 2^-126, finfo(f32).tiny
  float u = fmaxf(tiny, f + tiny);                  // f*(1-tiny)+tiny folds to f+tiny
  float l1 = (float)log((double)u);                 // f32-rounded inner log
  return -(float)log(-(double)l1);                  // f32-rounded outer log, negated
}

// ---------------- xg precompute: emb[v] @ Wih.T + bih + bhh ----------------
__global__ void k_xg(const float* __restrict__ emb,
                     const float* __restrict__ WihF, const float* __restrict__ bihF,
                     const float* __restrict__ bhhF,
                     const float* __restrict__ WihB, const float* __restrict__ bihB,
                     const float* __restrict__ bhhB,
                     float* __restrict__ ws) {
  __shared__ float se[1536];
  const int tid = threadIdx.x;
  for (int i = tid; i < 1536; i += 256) se[i] = emb[i];
  __syncthreads();
  const int gid = blockIdx.x * 256 + tid;  // 0..2047
  const int d = gid >> 10, r = gid & 1023;
  const float* Wih = d ? WihB : WihF;
  const float* bih = d ? bihB : bihF;
  const float* bhh = d ? bhhB : bhhF;
  float acc[6] = {0.f, 0.f, 0.f, 0.f, 0.f, 0.f};
  const float4* wr = (const float4*)(Wih + r * 256);
  for (int c = 0; c < 64; c++) {
    float4 wv = wr[c];
#pragma unroll
    for (int v = 0; v < 6; v++) {
      const float* ev = &se[v * 256 + 4 * c];
      acc[v] += wv.x * ev[0] + wv.y * ev[1] + wv.z * ev[2] + wv.w * ev[3];
    }
  }
  const float bsum = bih[r] + bhh[r];
#pragma unroll
  for (int v = 0; v < 6; v++) ws[XG_OFF + d * 6144 + v * 1024 + r] = acc[v] + bsum;
}

// ---------------- chain kernel: one block (2048 steps), both directions ----------------
// grid 16: blocks 0..7 = fwd slices, 8..15 = bwd slices.
// Slice k owns h elems [32k,32k+32); wave w = gate type w (i,f,g,o).
// Lane (q,p): rows 256w + 32k + 8q + [0,8), cols 16p + [0,16) held in VGPRs.
__global__ __launch_bounds__(256, 1)
void k_chain(const int* __restrict__ arc, const float* __restrict__ h0,
             const float* __restrict__ c0, const float* __restrict__ WhhF,
             const float* __restrict__ WhhB, float* __restrict__ ws,
             float* __restrict__ out, int b) {
  const int tid = threadIdx.x;
  const int d = blockIdx.x >> 3;
  const int k = blockIdx.x & 7;
  const int w = tid >> 6;
  const int lane = tid & 63;
  const int q = lane >> 4, p = lane & 15;

  __shared__ float xg_s[6 * 1024];
  __shared__ int arc_s[2048];
  __shared__ float h_s[16 * 20];  // 16 chunks of 16 floats, stride 20 (16B-aligned, no conflicts)

  const float* Whh = d ? WhhB : WhhF;
  for (int i = tid; i < 6144; i += 256) xg_s[i] = ws[XG_OFF + d * 6144 + i];
  {
    const int* ab = arc + b * 2048;
    for (int i = tid; i < 2048; i += 256) arc_s[i] = ab[i];
  }
  // weights into registers
  float4 W[8][4];
  const int e0 = 32 * k + 8 * q;
#pragma unroll
  for (int i = 0; i < 8; i++) {
    const float* rp = Whh + (256 * w + e0 + i) * 256 + 16 * p;
#pragma unroll
    for (int j = 0; j < 4; j++) W[i][j] = ((const float4*)rp)[j];
  }
  float hval, cval;
  if (b == 0) { hval = h0[d * 256 + tid]; cval = c0[d * 256 + tid]; }
  else        { hval = ws[SH_OFF + d * 256 + tid]; cval = ws[SC_OFF + d * 256 + tid]; }
  h_s[(tid >> 4) * 20 + (tid & 15)] = hval;
  __syncthreads();
  float4 hw[4];
  {
    const float4* hp = (const float4*)&h_s[p * 20];
#pragma unroll
    for (int j = 0; j < 4; j++) hw[j] = hp[j];
  }
  unsigned long long* gp =
      reinterpret_cast<unsigned long long*>(ws + GP_OFF_F) + (unsigned)d * 2048u;
  const bool writer = (p < 8);
  const int wElem = e0 + p;  // elem this lane publishes (if writer)
  float* histD = ws + HIST_OFF + d * HIST_D;
  const bool histWG = (k == 0);

  for (int t = 0; t < 2048; t++) {
    const int sym = arc_s[d ? (2047 - t) : t];
    // partial matvec: 8 rows x 16 cols per lane
    float acc[8];
#pragma unroll
    for (int i = 0; i < 8; i++) {
      float a;
      a  = W[i][0].x * hw[0].x;
      a += W[i][0].y * hw[0].y;
      a += W[i][0].z * hw[0].z;
      a += W[i][0].w * hw[0].w;
      a += W[i][1].x * hw[1].x;
      a += W[i][1].y * hw[1].y;
      a += W[i][1].z * hw[1].z;
      a += W[i][1].w * hw[1].w;
      a += W[i][2].x * hw[2].x;
      a += W[i][2].y * hw[2].y;
      a += W[i][2].z * hw[2].z;
      a += W[i][2].w * hw[2].w;
      a += W[i][3].x * hw[3].x;
      a += W[i][3].y * hw[3].y;
      a += W[i][3].z * hw[3].z;
      a += W[i][3].w * hw[3].w;
      acc[i] = a;
    }
    // 16-lane butterfly reduce (quarter-wave)
#pragma unroll
    for (int i = 0; i < 8; i++) {
      float v = acc[i];
      v += __shfl_xor(v, 1, 16);
      v += __shfl_xor(v, 2, 16);
      v += __shfl_xor(v, 4, 16);
      v += __shfl_xor(v, 8, 16);
      acc[i] = v;
    }
    // publish gates (stamped 8B pairs, no fences needed)
    if (writer) {
      float g = acc[0];
      g = (p == 1) ? acc[1] : g;
      g = (p == 2) ? acc[2] : g;
      g = (p == 3) ? acc[3] : g;
      g = (p == 4) ? acc[4] : g;
      g = (p == 5) ? acc[5] : g;
      g = (p == 6) ? acc[6] : g;
      g = (p == 7) ? acc[7] : g;
      g += xg_s[sym * 1024 + 256 * w + wElem];
      unsigned long long pk = (unsigned long long)__float_as_uint(g) |
                              ((unsigned long long)(unsigned)(t + 1) << 32);
      __hip_atomic_store(&gp[(unsigned)((t & 1) * 1024 + wElem * 4 + w)], pk,
                         __ATOMIC_RELAXED, __HIP_MEMORY_SCOPE_AGENT);
    }
    // consume 4 gates for elem = tid
    const unsigned stamp = (unsigned)(t + 1);
    unsigned long long v0, v1, v2, v3;
    unsigned long long* base = gp + (unsigned)((t & 1) * 1024 + tid * 4);
    for (;;) {
      v0 = __hip_atomic_load(base + 0, __ATOMIC_RELAXED, __HIP_MEMORY_SCOPE_AGENT);
      v1 = __hip_atomic_load(base + 1, __ATOMIC_RELAXED, __HIP_MEMORY_SCOPE_AGENT);
      v2 = __hip_atomic_load(base + 2, __ATOMIC_RELAXED, __HIP_MEMORY_SCOPE_AGENT);
      v3 = __hip_atomic_load(base + 3, __ATOMIC_RELAXED, __HIP_MEMORY_SCOPE_AGENT);
      bool ok = ((unsigned)(v0 >> 32) == stamp) & ((unsigned)(v1 >> 32) == stamp) &
                ((unsigned)(v2 >> 32) == stamp) & ((unsigned)(v3 >> 32) == stamp);
      if (__all(ok)) break;
    }
    const float gi = __uint_as_float((unsigned)v0);
    const float gf = __uint_as_float((unsigned)v1);
    const float gg = __uint_as_float((unsigned)v2);
    const float go = __uint_as_float((unsigned)v3);
    const float I = 1.0f / (1.0f + expf(-gi));
    const float F = 1.0f / (1.0f + expf(-gf));
    const float G = tanhf(gg);
    const float O = 1.0f / (1.0f + expf(-go));
    cval = F * cval + I * G;
    hval = O * tanhf(cval);
    if (histWG) histD[t * 256 + tid] = hval;
    __syncthreads();  // all waves done reading old h_s (their hw reload)
    h_s[(tid >> 4) * 20 + (tid & 15)] = hval;
    __syncthreads();  // h_s writes visible
    {
      const float4* hp = (const float4*)&h_s[p * 20];
#pragma unroll
      for (int j = 0; j < 4; j++) hw[j] = hp[j];
    }
  }
  if (histWG) {
    ws[SH_OFF + d * 256 + tid] = hval;
    ws[SC_OFF + d * 256 + tid] = cval;
    if (b == 15) {
      out[OUT_H + d * 256 + tid] = hval;
      out[OUT_C + d * 256 + tid] = cval;
    }
  }
}

// ---------------- sampler: one block's FC + gumbel-argmax + ce/ent ----------------
__global__ void k_sampler(const float* __restrict__ fcW, const float* __restrict__ fcb,
                          float* __restrict__ ws, float* __restrict__ out, int b) {
  const int tid = threadIdx.x;
  __shared__ float sW[5 * 512];
  __shared__ float sb[5];
  __shared__ float red[256];
  for (int i = tid; i < 2560; i += 256) sW[i] = fcW[i];
  if (tid < 5) sb[tid] = fcb[tid];
  __syncthreads();
  // exact split chain, jax_threefry_partitionable=True (modern default):
  // key_{i+1} = threefry(key_i, (0,0)); sub_i = threefry(key_i, (0,1))
  uint32_t s0 = 0u, s1 = 0u;
  {
    uint32_t k0 = 0u, k1 = 42u;
    for (int i = 0; i <= b; i++) {
      uint32_t n0, n1, t0, t1;
      tf2x32(k0, k1, 0u, 0u, n0, n1);  // new key (both output words)
      tf2x32(k0, k1, 0u, 1u, t0, t1);  // sub (both output words)
      s0 = t0; s1 = t1;
      k0 = n0; k1 = n1;
    }
  }
  const int pp = blockIdx.x * 256 + tid;  // 0..1023; handles positions pp and pp+1024
  const float* histF = ws + HIST_OFF;
  const float* histB = ws + HIST_OFF + HIST_D;
  float dotL[5] = {0.f, 0.f, 0.f, 0.f, 0.f};
  float dotH[5] = {0.f, 0.f, 0.f, 0.f, 0.f};
  const float4* hfL = (const float4*)(histF + pp * 256);
  const float4* hbL = (const float4*)(histB + (2047 - pp) * 256);
  const float4* hfH = (const float4*)(histF + (pp + 1024) * 256);
  const float4* hbH = (const float4*)(histB + (1023 - pp) * 256);
  for (int c = 0; c < 64; c++) {
    float4 a = hfL[c], bb = hbL[c], e = hfH[c], f = hbH[c];
#pragma unroll
    for (int j = 0; j < 5; j++) {
      const float* wr = &sW[j * 512 + 4 * c];
      dotL[j] += a.x * wr[0] + a.y * wr[1] + a.z * wr[2] + a.w * wr[3];
      dotL[j] += bb.x * wr[256] + bb.y * wr[257] + bb.z * wr[258] + bb.w * wr[259];
      dotH[j] += e.x * wr[0] + e.y * wr[1] + e.z * wr[2] + e.w * wr[3];
      dotH[j] += f.x * wr[256] + f.y * wr[257] + f.z * wr[258] + f.w * wr[259];
    }
  }
  // gumbel bits, partitionable random_bits (bit_width=32):
  // bits(n) = y0 ^ y1 of threefry(sub, (hi32(n)=0, lo32(n)=n)), n = 5t+j row-major
  uint32_t bl[5], bh[5];
#pragma unroll
  for (int j = 0; j < 5; j++) {
    uint32_t y0, y1;
    tf2x32(s0, s1, 0u, (uint32_t)(5 * pp + j), y0, y1);
    bl[j] = y0 ^ y1;
    tf2x32(s0, s1, 0u, (uint32_t)(5 * (pp + 1024) + j), y0, y1);
    bh[j] = y0 ^ y1;
  }
  const float OPT = (float)(1.1 / 2.5);
  float ce_acc = 0.f, ent_acc = 0.f;
#pragma unroll
  for (int half = 0; half < 2; half++) {
    const int t = half ? (pp + 1024) : pp;
    float l[5];
#pragma unroll
    for (int j = 0; j < 5; j++) {
      float dv = half ? dotH[j] : dotL[j];
      l[j] = OPT * tanhf((dv + sb[j]) / 5.0f);
    }
    int idx = 0;
    float best;
    {
      uint32_t b0 = half ? bh[0] : bl[0];
      best = gumbel_from_bits(b0) + l[0];
    }
#pragma unroll
    for (int j = 1; j < 5; j++) {
      uint32_t bj = half ? bh[j] : bl[j];
      float v = gumbel_from_bits(bj) + l[j];
      if (v > best) { best = v; idx = j; }
    }
    out[b * 2048 + t] = (float)idx;
    float m = l[0];
#pragma unroll
    for (int j = 1; j < 5; j++) m = fmaxf(m, l[j]);
    float ssum = 0.f;
#pragma unroll
    for (int j = 0; j < 5; j++) ssum += expf(l[j] - m);
    float lse = logf(ssum);
    float lpidx = 0.f;
#pragma unroll
    for (int j = 0; j < 5; j++) {
      float lp = (l[j] - m) - lse;
      ent_acc -= lp * expf(lp);
      lpidx = (j == idx) ? lp : lpidx;
    }
    ce_acc -= lpidx;
  }
  // block reduction
  red[tid] = ce_acc; __syncthreads();
  for (int s = 128; s > 0; s >>= 1) {
    if (tid < s) red[tid] += red[tid + s];
    __syncthreads();
  }
  if (tid == 0) ws[CEP_OFF + b * 4 + blockIdx.x] = red[0];
  __syncthreads();
  red[tid] = ent_acc; __syncthreads();
  for (int s = 128; s > 0; s >>= 1) {
    if (tid < s) red[tid] += red[tid + s];
    __syncthreads();
  }
  if (tid == 0) ws[ENTP_OFF + b * 4 + blockIdx.x] = red[0];
}

// ---------------- final reduce ----------------
__global__ void k_final(const float* __restrict__ ws, float* __restrict__ out) {
  if (threadIdx.x == 0 && blockIdx.x == 0) {
    float ce = 0.f, ent = 0.f;
    for (int b = 0; b < 16; b++) {
      float cb = 0.f, eb = 0.f;
      for (int j = 0; j < 4; j++) {
        cb += ws[CEP_OFF + b * 4 + j];
        eb += ws[ENTP_OFF + b * 4 + j];
      }
      ce += cb / 2048.0f;
      ent += eb / 10240.0f;
    }
    out[OUT_CE] = ce;
    out[OUT_CE + 1] = ent;
  }
}

extern "C" void kernel_launch(void* const* d_in, const int* in_sizes, int n_in,
                              void* d_out, int out_size, void* d_ws, size_t ws_size,
                              hipStream_t stream) {
  (void)in_sizes; (void)n_in; (void)out_size; (void)ws_size;
  const int* arc = (const int*)d_in[0];
  const float* h0 = (const float*)d_in[1];
  const float* c0 = (const float*)d_in[2];
  const float* emb = (const float*)d_in[3];
  const float* WihF = (const float*)d_in[4];
  const float* WhhF = (const float*)d_in[5];
  const float* bihF = (const float*)d_in[6];
  const float* bhhF = (const float*)d_in[7];
  const float* WihB = (const float*)d_in[8];
  const float* WhhB = (const float*)d_in[9];
  const float* bihB = (const float*)d_in[10];
  const float* bhhB = (const float*)d_in[11];
  const float* fcW = (const float*)d_in[12];
  const float* fcb = (const float*)d_in[13];
  float* out = (float*)d_out;
  float* ws = (float*)d_ws;

  hipLaunchKernelGGL(k_xg, dim3(8), dim3(256), 0, stream,
                     emb, WihF, bihF, bhhF, WihB, bihB, bhhB, ws);
  for (int b = 0; b < 16; b++) {
    hipLaunchKernelGGL(k_chain, dim3(16), dim3(256), 0, stream,
                       arc, h0, c0, WhhF, WhhB, ws, out, b);
    hipLaunchKernelGGL(k_sampler, dim3(4), dim3(256), 0, stream,
                       fcW, fcb, ws, out, b);
  }
  hipLaunchKernelGGL(k_final, dim3(1), dim3(64), 0, stream, ws, out);
}